// Round 12
// baseline (142.667 us; speedup 1.0000x reference)
//
#include <hip/hip_runtime.h>

typedef float f4 __attribute__((ext_vector_type(4)));
typedef float f2 __attribute__((ext_vector_type(2)));

#define NPIX (32*512*512)        // 8388608
#define BN_EPS 1e-5f

// ws float layout (memset clears first 2048 bytes = floats 0..511):
// [0..5]    M1 sums of s_i
// [6..26]   M2 sums (upper tri, idx = 6 + a*(11-a)/2 + b, a<=b)
// [27]      S1 (sum o_pre), [28] S2 (sum o_pre^2)
// [29]      a2, [30] c2
// [32..480) wpack2[28][16] = {w0,w0,w1,w1,w2,w2,w3,w3,w4,w4,w5,w5,be,be,wo,wo}
//           (channels 25..27 stay all-zero -> contribute 0)
// [496]     zbuf (zero region; loadrows touches floats 495..500)

struct Rows { f4 C, N, S; float wv, ev, nwv, sev; };

__device__ __forceinline__ Rows loadrows(const float* __restrict__ x,
                                         const float* zbuf, int p) {
    Rows r;
    int rem = p & (512*512 - 1);
    int i = rem >> 9, jj = rem & 511;          // jj multiple of 4
    const float* xc = x + p;
    const float* xn = (i > 0)   ? xc - 512 : zbuf;
    const float* xs = (i < 511) ? xc + 512 : zbuf;
    r.C = *(const f4*)xc;
    r.N = *(const f4*)xn;
    r.S = *(const f4*)xs;
    bool hw = (jj > 0), he = (jj < 508);
    float wv  = xc[hw ? -1 : 0];
    float ev  = xc[he ?  4 : 3];
    float nwv = xn[hw ? -1 : 0];
    float sev = xs[he ?  4 : 3];
    r.wv  = hw ? wv  : 0.f;
    r.ev  = he ? ev  : 0.f;
    r.nwv = hw ? nwv : 0.f;
    r.sev = he ? sev : 0.f;
    return r;
}

__device__ __forceinline__ void mkstencil(const Rows& r, f4* s) {
    f4 E   = {r.C.y, r.C.z, r.C.w, r.ev};
    f4 W   = {r.wv,  r.C.x, r.C.y, r.C.z};
    f4 Ssh = {r.S.y, r.S.z, r.S.w, r.sev};
    f4 Nsh = {r.nwv, r.N.x, r.N.y, r.N.z};
    s[0] = r.C;
    s[1] = (r.S - r.N) * 0.5f;
    s[2] = (E - W) * 0.5f;
    s[3] = r.S + r.N - 2.f*r.C;
    s[4] = E + W - 2.f*r.C;
    s[5] = Ssh + Nsh - r.S - E;
}

// ---------------- k_moments: 16 px/thread, SCALAR accumulators ----------------
__global__ __launch_bounds__(256) void k_moments(const float* __restrict__ x,
                                                 float* ws) {
    const float* zbuf = ws + 496;
    int t = threadIdx.x;
    int g0 = blockIdx.x * 1024 + t;            // first f4-group of this thread
    float acc[27];
    #pragma unroll
    for (int i = 0; i < 27; ++i) acc[i] = 0.f;

    #pragma unroll
    for (int q = 0; q < 4; ++q) {
        Rows r = loadrows(x, zbuf, (g0 + 256*q) * 4);
        f4 s[6];
        mkstencil(r, s);
        #pragma unroll
        for (int a = 0; a < 6; ++a) {
            acc[a] += (s[a].x + s[a].y) + (s[a].z + s[a].w);
            #pragma unroll
            for (int b = a; b < 6; ++b) {
                int idx = 6 + a*(11-a)/2 + b;
                float v = acc[idx];
                v = fmaf(s[a].x, s[b].x, v);
                v = fmaf(s[a].y, s[b].y, v);
                v = fmaf(s[a].z, s[b].z, v);
                v = fmaf(s[a].w, s[b].w, v);
                acc[idx] = v;
            }
        }
    }
    __shared__ float red[27][4];
    int wave = t >> 6, lane = t & 63;
    #pragma unroll
    for (int i = 0; i < 27; ++i) {
        float v = acc[i];
        for (int off = 32; off; off >>= 1) v += __shfl_xor(v, off);
        if (lane == 0) red[i][wave] = v;
    }
    __syncthreads();
    if (t < 27) atomicAdd(&ws[t], red[t][0] + red[t][1] + red[t][2] + red[t][3]);
}

__global__ void k_stats1(const float* w1, const float* b1, const float* g1,
                         const float* beta1, const float* w2, float* ws) {
    int c = threadIdx.x;
    if (c >= 25) return;
    const float invN = 1.f / (float)NPIX;
    float m1[6], wr[6];
    #pragma unroll
    for (int i = 0; i < 6; ++i) m1[i] = ws[i] * invN;
    #pragma unroll
    for (int i = 0; i < 6; ++i) wr[i] = w1[c*6 + i];
    float bc = b1[c];
    float mean = bc;
    #pragma unroll
    for (int i = 0; i < 6; ++i) mean = fmaf(wr[i], m1[i], mean);
    float e2 = bc * bc;
    #pragma unroll
    for (int i = 0; i < 6; ++i) e2 = fmaf(2.f*bc*wr[i], m1[i], e2);
    #pragma unroll
    for (int i = 0; i < 6; ++i)
        #pragma unroll
        for (int j = 0; j < 6; ++j) {
            int a = i < j ? i : j, b = i < j ? j : i;
            float m2 = ws[6 + a*(11-a)/2 + b] * invN;
            e2 = fmaf(wr[i]*wr[j], m2, e2);
        }
    float var = e2 - mean*mean;
    float a1 = g1[c] * rsqrtf(var + BN_EPS);
    float* wp = ws + 32 + c*16;
    #pragma unroll
    for (int i = 0; i < 6; ++i) { wp[2*i] = a1 * wr[i]; wp[2*i+1] = a1 * wr[i]; }
    float be = fmaf(a1, bc - mean, beta1[c]);
    wp[12] = be;    wp[13] = be;
    wp[14] = w2[c]; wp[15] = w2[c];
}

// -------- k_main: 16 px/thread, pk_fma conv, SGPR-pair weights (7 groups x 4 ch) --------
__global__ __launch_bounds__(256) void k_main(const float* __restrict__ x,
                                              const float* __restrict__ wts,
                                              const float* __restrict__ zbuf,
                                              const float* __restrict__ b2,
                                              float* __restrict__ stats,
                                              float* __restrict__ opre) {
    int t = threadIdx.x;
    int g0 = blockIdx.x * 1024 + t;            // first f4-group of this thread

    // build all 4 stencils up front; view as f2 halves for pk ops
    f4 s[4][6];
    #pragma unroll
    for (int q = 0; q < 4; ++q) {
        Rows r = loadrows(x, zbuf, (g0 + 256*q) * 4);
        mkstencil(r, s[q]);
    }

    float b2v = b2[0];
    f2 o2[4][2];
    #pragma unroll
    for (int q = 0; q < 4; ++q) {
        o2[q][0] = (f2){b2v, b2v};
        o2[q][1] = (f2){b2v, b2v};
    }

    // 7 groups of 4 channels; 64 weight floats/group live in SGPRs.
    // '#pragma unroll 1' keeps only one group's weights live.
    #pragma unroll 1
    for (int g = 0; g < 7; ++g) {
        const f2* wg = (const f2*)(wts + g * 64);
        #pragma unroll
        for (int c = 0; c < 4; ++c) {
            f2 W0 = wg[c*8+0], W1 = wg[c*8+1], W2 = wg[c*8+2];
            f2 W3 = wg[c*8+3], W4 = wg[c*8+4], W5 = wg[c*8+5];
            f2 BE = wg[c*8+6], WO = wg[c*8+7];
            #pragma unroll
            for (int q = 0; q < 4; ++q) {
                #pragma unroll
                for (int h = 0; h < 2; ++h) {
                    f2 sp0 = h ? s[q][0].zw : s[q][0].xy;
                    f2 sp1 = h ? s[q][1].zw : s[q][1].xy;
                    f2 sp2 = h ? s[q][2].zw : s[q][2].xy;
                    f2 sp3 = h ? s[q][3].zw : s[q][3].xy;
                    f2 sp4 = h ? s[q][4].zw : s[q][4].xy;
                    f2 sp5 = h ? s[q][5].zw : s[q][5].xy;
                    f2 tt;
                    asm("v_pk_mul_f32 %0, %1, %2"
                        : "=v"(tt) : "s"(W0), "v"(sp0));
                    asm("v_pk_fma_f32 %0, %1, %2, %0"
                        : "+v"(tt) : "s"(W1), "v"(sp1));
                    asm("v_pk_fma_f32 %0, %1, %2, %0"
                        : "+v"(tt) : "s"(W2), "v"(sp2));
                    asm("v_pk_fma_f32 %0, %1, %2, %0"
                        : "+v"(tt) : "s"(W3), "v"(sp3));
                    asm("v_pk_fma_f32 %0, %1, %2, %0"
                        : "+v"(tt) : "s"(W4), "v"(sp4));
                    asm("v_pk_fma_f32 %0, %1, %2, %0"
                        : "+v"(tt) : "s"(W5), "v"(sp5));
                    asm("v_pk_add_f32 %0, %1, %0"
                        : "+v"(tt) : "s"(BE));
                    tt.x = fmaxf(tt.x, 0.f);
                    tt.y = fmaxf(tt.y, 0.f);
                    asm("v_pk_fma_f32 %0, %1, %2, %0"
                        : "+v"(o2[q][h]) : "s"(WO), "v"(tt));
                }
            }
        }
    }

    float l1 = 0.f, l2 = 0.f;
    #pragma unroll
    for (int q = 0; q < 4; ++q) {
        f4 O = {o2[q][0].x, o2[q][0].y, o2[q][1].x, o2[q][1].y};
        *(f4*)(opre + (g0 + 256*q) * 4) = O;
        l1 += (O.x + O.y) + (O.z + O.w);
        l2 = fmaf(O.x, O.x, l2); l2 = fmaf(O.y, O.y, l2);
        l2 = fmaf(O.z, O.z, l2); l2 = fmaf(O.w, O.w, l2);
    }
    for (int off = 32; off; off >>= 1) { l1 += __shfl_xor(l1, off); l2 += __shfl_xor(l2, off); }
    __shared__ float red[2][4];
    int wave = t >> 6, lane = t & 63;
    if (lane == 0) { red[0][wave] = l1; red[1][wave] = l2; }
    __syncthreads();
    if (t == 0) atomicAdd(&stats[27], red[0][0]+red[0][1]+red[0][2]+red[0][3]);
    if (t == 1) atomicAdd(&stats[28], red[1][0]+red[1][1]+red[1][2]+red[1][3]);
}

__global__ void k_stats2(const float* g2, const float* beta2, float* ws) {
    const float invN = 1.f / (float)NPIX;
    float mean = ws[27] * invN;
    float var  = ws[28] * invN - mean*mean;
    float a2 = g2[0] * rsqrtf(var + BN_EPS);
    ws[29] = a2;
    ws[30] = fmaf(-mean, a2, beta2[0]);
}

__global__ __launch_bounds__(256) void k_final(const float* __restrict__ x,
                                               const float* __restrict__ ws,
                                               float* __restrict__ out) {
    int idx = blockIdx.x * 256 + threadIdx.x;  // f4 index, 8192 blocks
    float a2 = ws[29], c2 = ws[30];
    f4 o  = ((const f4*)out)[idx];
    f4 xv = ((const f4*)x)[idx];
    f4 r;
    r.x = fmaxf(fmaf(a2, o.x, c2), 0.f) + xv.x;
    r.y = fmaxf(fmaf(a2, o.y, c2), 0.f) + xv.y;
    r.z = fmaxf(fmaf(a2, o.z, c2), 0.f) + xv.z;
    r.w = fmaxf(fmaf(a2, o.w, c2), 0.f) + xv.w;
    ((f4*)out)[idx] = r;
}

extern "C" void kernel_launch(void* const* d_in, const int* in_sizes, int n_in,
                              void* d_out, int out_size, void* d_ws, size_t ws_size,
                              hipStream_t stream) {
    const float* x     = (const float*)d_in[0];
    const float* w1    = (const float*)d_in[1];
    const float* b1    = (const float*)d_in[2];
    const float* g1    = (const float*)d_in[3];
    const float* beta1 = (const float*)d_in[4];
    const float* w2    = (const float*)d_in[5];
    const float* b2    = (const float*)d_in[6];
    const float* g2    = (const float*)d_in[7];
    const float* beta2 = (const float*)d_in[8];
    float* out = (float*)d_out;
    float* ws  = (float*)d_ws;

    hipMemsetAsync(ws, 0, 2048, stream);
    k_moments<<<2048, 256, 0, stream>>>(x, ws);
    k_stats1 <<<1, 32, 0, stream>>>(w1, b1, g1, beta1, w2, ws);
    k_main   <<<2048, 256, 0, stream>>>(x, ws + 32, ws + 496, b2, ws, out);
    k_stats2 <<<1, 1, 0, stream>>>(g2, beta2, ws);
    k_final  <<<8192, 256, 0, stream>>>(x, ws, out);
}